// Round 1
// baseline (306.112 us; speedup 1.0000x reference)
//
#include <hip/hip_runtime.h>

// VQ-VAE quantization: B=32, C=D=64, H=W=64 (NCHW), K=512 codes.
// out[0..N*D)   = quantized (NCHW), out[N*D] = loss = 1.25 * mean((q-x)^2)
#define DD     64
#define HW     4096        // H*W
#define KK     512
#define NROWS  131072      // B*H*W
#define CHUNK  128         // codebook rows per LDS stage (32 KB)

__global__ __launch_bounds__(256) void vq_main(
    const float* __restrict__ x, const float* __restrict__ emb,
    float* __restrict__ out, float* __restrict__ partial)
{
    __shared__ float sE[CHUNK * DD];   // 32 KB staged codebook chunk
    __shared__ float sE2[KK];          // 2 KB  ||e_k||^2
    __shared__ float sRed[4];

    const int tid = threadIdx.x;
    const int n   = blockIdx.x * 256 + tid;   // row id over (b,h,w)
    const int b   = n >> 12;                  // / 4096
    const int hw  = n & 4095;
    const float* xp = x + (size_t)b * (DD * HW) + hw;

    // ||e_k||^2 for all K (each thread does 2 rows; table is L2-hot)
    for (int k = tid; k < KK; k += 256) {
        const float* ep = emb + k * DD;
        float s = 0.f;
        #pragma unroll
        for (int c = 0; c < DD; c += 4) {
            float4 e = *(const float4*)(ep + c);
            s += e.x*e.x + e.y*e.y + e.z*e.z + e.w*e.w;
        }
        sE2[k] = s;
    }

    // x row -> registers (lane-coalesced per channel: lanes vary in w)
    float xr[DD];
    #pragma unroll
    for (int c = 0; c < DD; ++c) xr[c] = xp[(size_t)c * HW];

    float best = 3.4e38f;
    int   bidx = 0;

    for (int ch = 0; ch < KK / CHUNK; ++ch) {
        __syncthreads();   // protect previous chunk's readers
        // stage chunk: 8192 floats = 2048 float4, 8 per thread, coalesced
        const float4* src = (const float4*)(emb + ch * CHUNK * DD);
        float4* dst = (float4*)sE;
        #pragma unroll
        for (int i = 0; i < (CHUNK * DD / 4) / 256; ++i)
            dst[tid + i * 256] = src[tid + i * 256];
        __syncthreads();

        #pragma unroll 1
        for (int kk = 0; kk < CHUNK; ++kk) {
            const float4* e4 = (const float4*)(sE + kk * DD);
            float a0 = 0.f, a1 = 0.f, a2 = 0.f, a3 = 0.f;
            #pragma unroll
            for (int i = 0; i < DD / 4; ++i) {
                float4 e = e4[i];              // broadcast ds_read_b128
                a0 = fmaf(xr[4*i+0], e.x, a0);
                a1 = fmaf(xr[4*i+1], e.y, a1);
                a2 = fmaf(xr[4*i+2], e.z, a2);
                a3 = fmaf(xr[4*i+3], e.w, a3);
            }
            const int k = ch * CHUNK + kk;
            const float score = fmaf(-2.f, (a0 + a1) + (a2 + a3), sE2[k]);
            if (score < best) { best = score; bidx = k; }   // strict <: first-occurrence argmin
        }
    }

    // write quantized row + accumulate (q-x)^2
    float lsum = 0.f;
    const float* eq = emb + bidx * DD;        // gather, L1/L2-hot table
    float* op = out + (size_t)b * (DD * HW) + hw;
    #pragma unroll
    for (int i = 0; i < DD / 4; ++i) {
        float4 q4 = *(const float4*)(eq + 4 * i);
        const float q[4] = {q4.x, q4.y, q4.z, q4.w};
        #pragma unroll
        for (int j = 0; j < 4; ++j) {
            const int c = 4 * i + j;
            op[(size_t)c * HW] = q[j];        // lane-coalesced store
            const float d = q[j] - xr[c];
            lsum = fmaf(d, d, lsum);
        }
    }

    // deterministic block reduction
    #pragma unroll
    for (int off = 32; off; off >>= 1) lsum += __shfl_down(lsum, off, 64);
    if ((tid & 63) == 0) sRed[tid >> 6] = lsum;
    __syncthreads();
    if (tid == 0) partial[blockIdx.x] = (sRed[0] + sRed[1]) + (sRed[2] + sRed[3]);
}

__global__ __launch_bounds__(256) void vq_loss(
    const float* __restrict__ partial, float* __restrict__ loss)
{
    __shared__ float sRed[4];
    float v = 0.f;
    for (int i = threadIdx.x; i < NROWS / 256; i += 256) v += partial[i];
    #pragma unroll
    for (int off = 32; off; off >>= 1) v += __shfl_down(v, off, 64);
    if ((threadIdx.x & 63) == 0) sRed[threadIdx.x >> 6] = v;
    __syncthreads();
    if (threadIdx.x == 0)
        loss[0] = ((sRed[0] + sRed[1]) + (sRed[2] + sRed[3])) * (1.25f / 8388608.0f);
}

extern "C" void kernel_launch(void* const* d_in, const int* in_sizes, int n_in,
                              void* d_out, int out_size, void* d_ws, size_t ws_size,
                              hipStream_t stream) {
    const float* x   = (const float*)d_in[0];   // [32,64,64,64] NCHW
    const float* emb = (const float*)d_in[1];   // [512,64]
    float* out     = (float*)d_out;             // N*D quantized + 1 loss
    float* partial = (float*)d_ws;              // 512 block partials

    vq_main<<<NROWS / 256, 256, 0, stream>>>(x, emb, out, partial);
    vq_loss<<<1, 256, 0, stream>>>(partial, out + (size_t)NROWS * DD);
}

// Round 2
// 53.325 us; speedup vs baseline: 5.7405x; 5.7405x over previous
//
#include <hip/hip_runtime.h>

// VQ-VAE quantization via fused bf16-MFMA argmin. B=32, D=64, HW=4096, K=512.
// out[0..8388608) = quantized (NCHW), out[8388608] = 1.25 * mean((q-x)^2)
#define KK      512
#define DD      64
#define HWSZ    4096
#define NROWS   131072
#define NBLK    1024
#define TPB     4          // 32-row tiles per block

typedef short short8 __attribute__((ext_vector_type(8)));
typedef float f32x16 __attribute__((ext_vector_type(16)));

static __device__ __forceinline__ unsigned f2bf(float f) {
    unsigned u = __builtin_bit_cast(unsigned, f);
    return (u + 0x7FFFu + ((u >> 16) & 1u)) >> 16;          // RNE f32->bf16
}
static __device__ __forceinline__ unsigned pk(float lo, float hi) {
    return f2bf(lo) | (f2bf(hi) << 16);
}
static __device__ __forceinline__ float    u2f(unsigned u) { return __builtin_bit_cast(float, u); }
static __device__ __forceinline__ unsigned f2u(float f)    { return __builtin_bit_cast(unsigned, f); }

__global__ __launch_bounds__(256, 2) void vq_mfma(
    const float* __restrict__ x, const float* __restrict__ emb,
    float* __restrict__ out, float* __restrict__ partial)
{
    __shared__ float    sH[KK];        // -0.5*||e_k||^2
    __shared__ unsigned sX[32 * 32];   // x tile: dword(cp,hw) = bf16(x[2cp][hw]) | bf16(x[2cp+1][hw])<<16
    __shared__ float    sKey[128];     // per-wave per-row best key
    __shared__ float    sRed[4];

    const int tid  = threadIdx.x;
    const int lane = tid & 63;
    const int w    = tid >> 6;         // wave 0..3, owns codes [w*128, w*128+128)
    const int g    = lane >> 5;        // k-group within wave
    const int wbase = w * 128;

    // ---- -e^2/2 table (cooperative) ----
    for (int k = tid; k < KK; k += 256) {
        const float* ep = emb + k * DD;
        float s = 0.f;
        #pragma unroll
        for (int c = 0; c < DD; c += 4) {
            float4 e = *(const float4*)(ep + c);
            s = fmaf(e.x, e.x, s); s = fmaf(e.y, e.y, s);
            s = fmaf(e.z, e.z, s); s = fmaf(e.w, e.w, s);
        }
        sH[k] = -0.5f * s;
    }
    __syncthreads();

    // ---- persistent codebook A-fragments + accumulator init (C = -e^2/2) ----
    short8 afrag[4][4];                // [code-tile][k-chunk]
    float  e2r[4][16];
    #pragma unroll
    for (int ct = 0; ct < 4; ++ct) {
        const int code = wbase + ct * 32 + (lane & 31);     // A row = lane&31 (verified C/D map family)
        #pragma unroll
        for (int m = 0; m < 4; ++m) {
            const float* ep = emb + code * DD + m * 16 + 8 * g;   // same k-map as B: consistent => sum invariant
            float4 a  = *(const float4*)ep;
            float4 b4 = *(const float4*)(ep + 4);
            union { unsigned u[4]; short8 s; } cv;
            cv.u[0] = pk(a.x, a.y);  cv.u[1] = pk(a.z, a.w);
            cv.u[2] = pk(b4.x, b4.y); cv.u[3] = pk(b4.z, b4.w);
            afrag[ct][m] = cv.s;
        }
        #pragma unroll
        for (int r = 0; r < 16; ++r)   // D row = (r&3) + 8*(r>>2) + 4*(lane>>5)   [m74/m101]
            e2r[ct][r] = sH[wbase + ct * 32 + (r & 3) + 8 * (r >> 2) + 4 * g];
    }

    float lsum = 0.f;

    for (int rt = 0; rt < TPB; ++rt) {
        const int R   = blockIdx.x * (32 * TPB) + rt * 32;
        const int b   = R >> 12;
        const int hw0 = R & 4095;
        const float* xb = x + (size_t)b * DD * HWSZ + hw0;

        __syncthreads();   // previous iteration's sX/sKey readers done
        {   // stage 32 rows x 64 ch, packed bf16 pairs along c
            const int cp = tid >> 3, hwq = (tid & 7) * 4;
            float4 fa = *(const float4*)(xb + (size_t)(2 * cp)     * HWSZ + hwq);
            float4 fb = *(const float4*)(xb + (size_t)(2 * cp + 1) * HWSZ + hwq);
            unsigned* dst = &sX[cp * 32 + hwq];
            dst[0] = pk(fa.x, fb.x); dst[1] = pk(fa.y, fb.y);
            dst[2] = pk(fa.z, fb.z); dst[3] = pk(fa.w, fb.w);
        }
        __syncthreads();

        // B fragments: col = hw = lane&31, k-chunk m
        short8 bfrag[4];
        #pragma unroll
        for (int m = 0; m < 4; ++m) {
            const unsigned* sp = &sX[(m * 8 + 4 * g) * 32 + (lane & 31)];
            union { unsigned u[4]; short8 s; } cv;
            cv.u[0] = sp[0]; cv.u[1] = sp[32]; cv.u[2] = sp[64]; cv.u[3] = sp[96];
            bfrag[m] = cv.s;
        }

        float kwave;
        #pragma unroll
        for (int ct = 0; ct < 4; ++ct) {
            f32x16 acc;
            #pragma unroll
            for (int r = 0; r < 16; ++r) acc[r] = e2r[ct][r];
            #pragma unroll
            for (int m = 0; m < 4; ++m)
                acc = __builtin_amdgcn_mfma_f32_32x32x16_bf16(afrag[ct][m], bfrag[m], acc, 0, 0, 0);
            // argmax via mantissa-packed keys: low 9 bits <- code, pure fmax trees
            float km;
            #pragma unroll
            for (int r = 0; r < 16; ++r) {
                unsigned key = (f2u(acc[r]) & 0xFFFFFE00u) |
                               (unsigned)((r & 3) + 8 * (r >> 2) + 4 * g);
                float fk = u2f(key);
                km = r ? fmaxf(km, fk) : fk;
            }
            unsigned kb = (f2u(km) & 0xFFFFFE00u) | (unsigned)(ct << 5) | (f2u(km) & 31u);
            float fkb = u2f(kb);
            kwave = ct ? fmaxf(kwave, fkb) : fkb;
        }
        float k2 = fmaxf(kwave, __shfl_xor(kwave, 32, 64));
        unsigned kb2 = (f2u(k2) & 0xFFFFFE00u) | (unsigned)(w << 7) | (f2u(k2) & 127u);
        if (lane < 32) sKey[w * 32 + lane] = u2f(kb2);
        __syncthreads();

        // output + loss: thread t -> row r = t&31, channels cg*8..cg*8+7
        const int r = tid & 31, cg = tid >> 5;
        float kf = fmaxf(fmaxf(sKey[r], sKey[32 + r]), fmaxf(sKey[64 + r], sKey[96 + r]));
        const int code = (int)(f2u(kf) & 511u);
        const float* eqp = emb + code * DD + cg * 8;
        float4 q0 = *(const float4*)eqp;
        float4 q1 = *(const float4*)(eqp + 4);
        float qv[8] = {q0.x, q0.y, q0.z, q0.w, q1.x, q1.y, q1.z, q1.w};
        float* ob = out + (size_t)b * DD * HWSZ + hw0;
        #pragma unroll
        for (int i = 0; i < 8; ++i) {
            const size_t off = (size_t)(cg * 8 + i) * HWSZ + r;
            float xv = xb[off];               // L2-hot re-read (exact fp32 loss)
            ob[off] = qv[i];
            float d = qv[i] - xv;
            lsum = fmaf(d, d, lsum);
        }
    }

    #pragma unroll
    for (int off = 32; off; off >>= 1) lsum += __shfl_down(lsum, off, 64);
    if (lane == 0) sRed[w] = lsum;
    __syncthreads();
    if (tid == 0) partial[blockIdx.x] = (sRed[0] + sRed[1]) + (sRed[2] + sRed[3]);
}

__global__ __launch_bounds__(256) void vq_loss(
    const float* __restrict__ partial, float* __restrict__ loss)
{
    __shared__ float sRed[4];
    float v = 0.f;
    #pragma unroll
    for (int i = 0; i < NBLK / 256; ++i) v += partial[threadIdx.x + i * 256];
    #pragma unroll
    for (int off = 32; off; off >>= 1) v += __shfl_down(v, off, 64);
    if ((threadIdx.x & 63) == 0) sRed[threadIdx.x >> 6] = v;
    __syncthreads();
    if (threadIdx.x == 0)
        loss[0] = ((sRed[0] + sRed[1]) + (sRed[2] + sRed[3])) * (1.25f / 8388608.0f);
}

extern "C" void kernel_launch(void* const* d_in, const int* in_sizes, int n_in,
                              void* d_out, int out_size, void* d_ws, size_t ws_size,
                              hipStream_t stream) {
    const float* x   = (const float*)d_in[0];   // [32,64,64,64] NCHW
    const float* emb = (const float*)d_in[1];   // [512,64]
    float* out     = (float*)d_out;
    float* partial = (float*)d_ws;              // NBLK floats

    vq_mfma<<<NBLK, 256, 0, stream>>>(x, emb, out, partial);
    vq_loss<<<1, 256, 0, stream>>>(partial, out + (size_t)NROWS * DD);
}

// Round 4
// 42.122 us; speedup vs baseline: 7.2672x; 1.2660x over previous
//
#include <hip/hip_runtime.h>

// VQ-VAE quantization via fused bf16-MFMA argmin, prefetch-pipelined.
// B=32, D=64, HW=4096, K=512. out[0..8388608)=quantized NCHW, out[8388608]=loss.
#define KK    512
#define DD    64
#define HWSZ  4096
#define NROWS 131072
#define TPB   4
#define NBLK  (NROWS / (32 * TPB))   // 1024

typedef short short8 __attribute__((ext_vector_type(8)));
typedef float f32x16 __attribute__((ext_vector_type(16)));

static __device__ __forceinline__ unsigned f2bf(float f) {
    unsigned u = __builtin_bit_cast(unsigned, f);
    return (u + 0x7FFFu + ((u >> 16) & 1u)) >> 16;          // RNE f32->bf16
}
static __device__ __forceinline__ unsigned pk2(float lo, float hi) {
    return f2bf(lo) | (f2bf(hi) << 16);                     // lo in bits 0..15
}
static __device__ __forceinline__ float    u2f(unsigned u) { return __builtin_bit_cast(float, u); }
static __device__ __forceinline__ unsigned f2u(float f)    { return __builtin_bit_cast(unsigned, f); }

#define FENCE() asm volatile("" ::: "memory")
// raw barrier: does NOT drain vmcnt -> prefetch loads stay in flight
#define BAR()       do { FENCE(); __builtin_amdgcn_s_barrier(); FENCE(); } while (0)
#define LGKM0_BAR() do { asm volatile("s_waitcnt lgkmcnt(0)" ::: "memory"); \
                         __builtin_amdgcn_s_barrier(); FENCE(); } while (0)

__global__ __launch_bounds__(256, 3) void vq_mfma(
    const float* __restrict__ x, const float* __restrict__ emb,
    float* __restrict__ out, float* __restrict__ partial)
{
    __shared__ float    sH[KK];        // -0.5*||e_k||^2 (fp32)
    __shared__ unsigned sX[32 * 32];   // dword(cp,hw) = bf16(x[2cp][hw]) | bf16(x[2cp+1][hw])<<16
    __shared__ float    sKey[128];     // per-wave per-row best packed key
    __shared__ float    sP2[128];      // per-wave per-row partial ||x||^2
    __shared__ float    sRed[4];

    const int tid  = threadIdx.x;
    const int lane = tid & 63;
    const int w    = tid >> 6;         // wave owns codes [w*128, w*128+128)
    const int g    = lane >> 5;
    const int wbase = w * 128;

    // ---- persistent codebook A-fragments; e^2 from the same loads ----
    short8 afrag[4][4];
    #pragma unroll
    for (int ct = 0; ct < 4; ++ct) {
        const int code = wbase + ct * 32 + (lane & 31);
        float e2h = 0.f;
        #pragma unroll
        for (int m = 0; m < 4; ++m) {
            const float* ep = emb + code * DD + m * 16 + 8 * g;
            float4 a  = *(const float4*)ep;
            float4 b4 = *(const float4*)(ep + 4);
            union { unsigned u[4]; short8 s; } cv;
            cv.u[0] = pk2(a.x, a.y);   cv.u[1] = pk2(a.z, a.w);
            cv.u[2] = pk2(b4.x, b4.y); cv.u[3] = pk2(b4.z, b4.w);
            afrag[ct][m] = cv.s;
            e2h = fmaf(a.x,a.x,e2h);  e2h = fmaf(a.y,a.y,e2h);
            e2h = fmaf(a.z,a.z,e2h);  e2h = fmaf(a.w,a.w,e2h);
            e2h = fmaf(b4.x,b4.x,e2h); e2h = fmaf(b4.y,b4.y,e2h);
            e2h = fmaf(b4.z,b4.z,e2h); e2h = fmaf(b4.w,b4.w,e2h);
        }
        float e2f = e2h + __shfl_xor(e2h, 32, 64);
        if (lane < 32) sH[code] = -0.5f * e2f;
    }
    __syncthreads();

    // ---- block geometry: 128 consecutive hw rows, b constant ----
    const int base = blockIdx.x * (32 * TPB);
    const int b    = base >> 12;
    const int hwb  = base & 4095;
    const float* xblk = x   + (size_t)b * (DD * HWSZ) + hwb;
    float*       oblk = out + (size_t)b * (DD * HWSZ) + hwb;

    const int cp  = tid >> 3;          // channel pair 0..31
    const int hwq = (tid & 7) * 4;     // hw quad
    const int rq  = tid & 7;           // epilogue: row quad
    const int c8  = tid >> 3;          // epilogue: channel pair

    float4 pfa = *(const float4*)(xblk + (size_t)(2*cp)   * HWSZ + hwq);
    float4 pfb = *(const float4*)(xblk + (size_t)(2*cp+1) * HWSZ + hwq);

    float lsum = 0.f;

    for (int rt = 0; rt < TPB; ++rt) {
        BAR();                                         // (A) prev readers done
        // ---- stage: pack bf16 pairs -> sX; row ||x||^2 partials -> sP2 ----
        {
            uint4 dw = { pk2(pfa.x, pfb.x), pk2(pfa.y, pfb.y),
                         pk2(pfa.z, pfb.z), pk2(pfa.w, pfb.w) };
            *(uint4*)&sX[cp * 32 + hwq] = dw;
        }
        float p0 = fmaf(pfa.x,pfa.x, pfb.x*pfb.x);
        float p1 = fmaf(pfa.y,pfa.y, pfb.y*pfb.y);
        float p2 = fmaf(pfa.z,pfa.z, pfb.z*pfb.z);
        float p3 = fmaf(pfa.w,pfa.w, pfb.w*pfb.w);
        #pragma unroll
        for (int off = 8; off <= 32; off <<= 1) {
            p0 += __shfl_xor(p0, off, 64); p1 += __shfl_xor(p1, off, 64);
            p2 += __shfl_xor(p2, off, 64); p3 += __shfl_xor(p3, off, 64);
        }
        if (lane < 8)
            *(float4*)&sP2[w * 32 + 4 * lane] = make_float4(p0, p1, p2, p3);
        LGKM0_BAR();                                   // (B) sX/sP2 ready

        // ---- prefetch next tile (stays in flight across (C)) ----
        if (rt + 1 < TPB) {
            const float* xb = xblk + (rt + 1) * 32;
            pfa = *(const float4*)(xb + (size_t)(2*cp)   * HWSZ + hwq);
            pfb = *(const float4*)(xb + (size_t)(2*cp+1) * HWSZ + hwq);
        }

        // ---- B fragments ----
        short8 bfrag[4];
        #pragma unroll
        for (int m = 0; m < 4; ++m) {
            const unsigned* sp = &sX[(m * 8 + 4 * g) * 32 + (lane & 31)];
            union { unsigned u[4]; short8 s; } cv;
            cv.u[0] = sp[0]; cv.u[1] = sp[32]; cv.u[2] = sp[64]; cv.u[3] = sp[96];
            bfrag[m] = cv.s;
        }

        // ---- 16 MFMA + mantissa-packed argmax ----
        float kwave;
        #pragma unroll
        for (int ct = 0; ct < 4; ++ct) {
            f32x16 acc;
            #pragma unroll
            for (int i = 0; i < 4; ++i) {              // broadcast b128: C = -e^2/2
                float4 h = *(const float4*)(sH + wbase + ct * 32 + 4 * g + 8 * i);
                acc[4*i] = h.x; acc[4*i+1] = h.y; acc[4*i+2] = h.z; acc[4*i+3] = h.w;
            }
            #pragma unroll
            for (int m = 0; m < 4; ++m)
                acc = __builtin_amdgcn_mfma_f32_32x32x16_bf16(afrag[ct][m], bfrag[m], acc, 0, 0, 0);
            float km;
            #pragma unroll
            for (int r = 0; r < 16; ++r) {
                unsigned key = (f2u(acc[r]) & 0xFFFFFE00u) |
                               (unsigned)((r & 3) + 8 * (r >> 2) + 4 * g);
                float fk = u2f(key);
                km = r ? fmaxf(km, fk) : fk;
            }
            unsigned kb = (f2u(km) & 0xFFFFFE00u) | (unsigned)(ct << 5) | (f2u(km) & 31u);
            float fkb = u2f(kb);
            kwave = ct ? fmaxf(kwave, fkb) : fkb;
        }
        float k2 = fmaxf(kwave, __shfl_xor(kwave, 32, 64));
        unsigned kb2 = (f2u(k2) & 0xFFFFFE00u) | (unsigned)(w << 7) | (f2u(k2) & 127u);
        if (lane < 32) sKey[w * 32 + lane] = u2f(kb2);
        LGKM0_BAR();                                   // (C) sKey ready

        // ---- epilogue: 4 rows x 2 channels per thread, float4 stores ----
        float4 qlo, qhi;
        #pragma unroll
        for (int j = 0; j < 4; ++j) {
            const int row = 4 * rq + j;
            float kf = fmaxf(fmaxf(sKey[row], sKey[32 + row]),
                             fmaxf(sKey[64 + row], sKey[96 + row]));
            const int code = (int)(f2u(kf) & 511u);
            if (c8 == 0) {                             // loss: ||x||^2 - 2*score
                float score = u2f(f2u(kf) & 0xFFFFFE00u);
                float x2 = (sP2[row] + sP2[32 + row]) + (sP2[64 + row] + sP2[96 + row]);
                lsum += fmaf(-2.f, score, x2);
            }
            float2 e = *(const float2*)(emb + code * DD + 2 * c8);
            if (j == 0) { qlo.x = e.x; qhi.x = e.y; }
            if (j == 1) { qlo.y = e.x; qhi.y = e.y; }
            if (j == 2) { qlo.z = e.x; qhi.z = e.y; }
            if (j == 3) { qlo.w = e.x; qhi.w = e.y; }
        }
        float* ob = oblk + rt * 32 + 4 * rq;
        *(float4*)(ob + (size_t)(2*c8)   * HWSZ) = qlo;
        *(float4*)(ob + (size_t)(2*c8+1) * HWSZ) = qhi;
    }

    // ---- deterministic block loss reduction ----
    #pragma unroll
    for (int off = 32; off; off >>= 1) lsum += __shfl_down(lsum, off, 64);
    if (lane == 0) sRed[w] = lsum;
    __syncthreads();
    if (tid == 0) partial[blockIdx.x] = (sRed[0] + sRed[1]) + (sRed[2] + sRed[3]);
}

__global__ __launch_bounds__(256) void vq_loss(
    const float* __restrict__ partial, float* __restrict__ loss)
{
    __shared__ float sRed[4];
    float v = 0.f;
    #pragma unroll
    for (int i = 0; i < NBLK / 256; ++i) v += partial[threadIdx.x + i * 256];
    #pragma unroll
    for (int off = 32; off; off >>= 1) v += __shfl_down(v, off, 64);
    if ((threadIdx.x & 63) == 0) sRed[threadIdx.x >> 6] = v;
    __syncthreads();
    if (threadIdx.x == 0)
        loss[0] = ((sRed[0] + sRed[1]) + (sRed[2] + sRed[3])) * (1.25f / 8388608.0f);
}

extern "C" void kernel_launch(void* const* d_in, const int* in_sizes, int n_in,
                              void* d_out, int out_size, void* d_ws, size_t ws_size,
                              hipStream_t stream) {
    const float* x   = (const float*)d_in[0];   // [32,64,64,64] NCHW
    const float* emb = (const float*)d_in[1];   // [512,64]
    float* out     = (float*)d_out;
    float* partial = (float*)d_ws;              // NBLK floats

    vq_mfma<<<NBLK, 256, 0, stream>>>(x, emb, out, partial);
    vq_loss<<<1, 256, 0, stream>>>(partial, out + (size_t)NROWS * DD);
}

// Round 5
// 39.800 us; speedup vs baseline: 7.6913x; 1.0584x over previous
//
#include <hip/hip_runtime.h>

// VQ-VAE quantization via fused bf16-MFMA argmin. One 128-row super-tile per
// block, 2 inner barriers. B=32, D=64, HW=4096, K=512.
// out[0..8388608)=quantized NCHW, out[8388608]=loss=1.25*mean((q-x)^2).
#define KK    512
#define DD    64
#define HWSZ  4096
#define NROWS 131072
#define RPB   128                  // rows per block
#define NBLK  (NROWS / RPB)        // 1024

typedef short short8 __attribute__((ext_vector_type(8)));
typedef float f32x16 __attribute__((ext_vector_type(16)));

static __device__ __forceinline__ unsigned f2bf(float f) {
    unsigned u = __builtin_bit_cast(unsigned, f);
    return (u + 0x7FFFu + ((u >> 16) & 1u)) >> 16;          // RNE f32->bf16
}
static __device__ __forceinline__ unsigned pk2(float lo, float hi) {
    return f2bf(lo) | (f2bf(hi) << 16);                     // lo in bits 0..15
}
static __device__ __forceinline__ float    u2f(unsigned u) { return __builtin_bit_cast(float, u); }
static __device__ __forceinline__ unsigned f2u(float f)    { return __builtin_bit_cast(unsigned, f); }

__global__ __launch_bounds__(256, 3) void vq_mfma(
    const float* __restrict__ x, const float* __restrict__ emb,
    float* __restrict__ out, float* __restrict__ partial)
{
    __shared__ float    sH[KK];          // -0.5*||e_k||^2 (fp32)
    __shared__ unsigned sX[4][32 * 32];  // 4 sub-tiles, packed bf16 pairs
    __shared__ float    sKey[4][4][32];  // [subtile][wave][row]: packed keys
    __shared__ float    sRed[4];

    const int tid  = threadIdx.x;
    const int lane = tid & 63;
    const int w    = tid >> 6;           // wave owns codes [w*128, w*128+128)
    const int g    = lane >> 5;
    const int wbase = w * 128;

    const int base = blockIdx.x * RPB;   // 128 consecutive hw rows, b constant
    const int b    = base >> 12;
    const int hwb  = base & 4095;
    const float* xblk = x   + (size_t)b * (DD * HWSZ) + hwb;
    float*       oblk = out + (size_t)b * (DD * HWSZ) + hwb;

    const int cp  = tid >> 3;            // staging: channel pair 0..31
    const int hwq = (tid & 7) * 4;       // staging: hw quad

    // ---- issue ALL x loads up front (8 float4 = 32 VGPR, latency hidden
    //      under A-frag setup VALU) ----
    float4 pfa[4], pfb[4];
    #pragma unroll
    for (int s = 0; s < 4; ++s) {
        const float* xb = xblk + 32 * s;
        pfa[s] = *(const float4*)(xb + (size_t)(2*cp)   * HWSZ + hwq);
        pfb[s] = *(const float4*)(xb + (size_t)(2*cp+1) * HWSZ + hwq);
    }

    // ---- persistent codebook A-fragments; -e^2/2 from the same loads ----
    short8 afrag[4][4];
    #pragma unroll
    for (int ct = 0; ct < 4; ++ct) {
        const int code = wbase + ct * 32 + (lane & 31);
        float e2h = 0.f;
        #pragma unroll
        for (int m = 0; m < 4; ++m) {
            const float* ep = emb + code * DD + m * 16 + 8 * g;
            float4 a  = *(const float4*)ep;
            float4 b4 = *(const float4*)(ep + 4);
            union { unsigned u[4]; short8 s; } cv;
            cv.u[0] = pk2(a.x, a.y);   cv.u[1] = pk2(a.z, a.w);
            cv.u[2] = pk2(b4.x, b4.y); cv.u[3] = pk2(b4.z, b4.w);
            afrag[ct][m] = cv.s;
            e2h = fmaf(a.x,a.x,e2h);   e2h = fmaf(a.y,a.y,e2h);
            e2h = fmaf(a.z,a.z,e2h);   e2h = fmaf(a.w,a.w,e2h);
            e2h = fmaf(b4.x,b4.x,e2h); e2h = fmaf(b4.y,b4.y,e2h);
            e2h = fmaf(b4.z,b4.z,e2h); e2h = fmaf(b4.w,b4.w,e2h);
        }
        float e2f = e2h + __shfl_xor(e2h, 32, 64);
        if (lane < 32) sH[code] = -0.5f * e2f;
    }

    // ---- pack x -> sX (all 4 sub-tiles); thread-local fp32 sum(x^2) ----
    float xsq = 0.f;
    #pragma unroll
    for (int s = 0; s < 4; ++s) {
        float4 fa = pfa[s], fb = pfb[s];
        uint4 dw = { pk2(fa.x, fb.x), pk2(fa.y, fb.y),
                     pk2(fa.z, fb.z), pk2(fa.w, fb.w) };
        *(uint4*)&sX[s][cp * 32 + hwq] = dw;
        xsq = fmaf(fa.x,fa.x,xsq); xsq = fmaf(fa.y,fa.y,xsq);
        xsq = fmaf(fa.z,fa.z,xsq); xsq = fmaf(fa.w,fa.w,xsq);
        xsq = fmaf(fb.x,fb.x,xsq); xsq = fmaf(fb.y,fb.y,xsq);
        xsq = fmaf(fb.z,fb.z,xsq); xsq = fmaf(fb.w,fb.w,xsq);
    }
    __syncthreads();                     // #1: sH + all sX ready

    // ---- compute: 4 sub-tiles back-to-back, NO barriers between ----
    #pragma unroll
    for (int s = 0; s < 4; ++s) {
        short8 bfrag[4];
        #pragma unroll
        for (int m = 0; m < 4; ++m) {
            const unsigned* sp = &sX[s][(m * 8 + 4 * g) * 32 + (lane & 31)];
            union { unsigned u[4]; short8 s8; } cv;
            cv.u[0] = sp[0]; cv.u[1] = sp[32]; cv.u[2] = sp[64]; cv.u[3] = sp[96];
            bfrag[m] = cv.s8;
        }
        float kwave;
        #pragma unroll
        for (int ct = 0; ct < 4; ++ct) {
            f32x16 acc;
            #pragma unroll
            for (int i = 0; i < 4; ++i) {           // broadcast b128: C = -e^2/2
                float4 h = *(const float4*)(sH + wbase + ct * 32 + 4 * g + 8 * i);
                acc[4*i] = h.x; acc[4*i+1] = h.y; acc[4*i+2] = h.z; acc[4*i+3] = h.w;
            }
            #pragma unroll
            for (int m = 0; m < 4; ++m)
                acc = __builtin_amdgcn_mfma_f32_32x32x16_bf16(afrag[ct][m], bfrag[m], acc, 0, 0, 0);
            float km;
            #pragma unroll
            for (int r = 0; r < 16; ++r) {          // mantissa-packed argmax keys
                unsigned key = (f2u(acc[r]) & 0xFFFFFE00u) |
                               (unsigned)((r & 3) + 8 * (r >> 2) + 4 * g);
                float fk = u2f(key);
                km = r ? fmaxf(km, fk) : fk;
            }
            unsigned kb = (f2u(km) & 0xFFFFFE00u) | (unsigned)(ct << 5) | (f2u(km) & 31u);
            float fkb = u2f(kb);
            kwave = ct ? fmaxf(kwave, fkb) : fkb;
        }
        float k2 = fmaxf(kwave, __shfl_xor(kwave, 32, 64));
        unsigned kb2 = (f2u(k2) & 0xFFFFFE00u) | (unsigned)(w << 7) | (f2u(k2) & 127u);
        if (lane < 32) sKey[s][w][lane] = u2f(kb2); // wave-private slice
    }
    __syncthreads();                     // #2: all sKey ready

    // ---- epilogue: thread = (row-quad q, channel-8-group cg) ----
    const int q  = tid & 31;             // rows 4q..4q+3
    const int cg = tid >> 5;             // channels 8cg..8cg+7
    const int s  = q >> 3;               // sub-tile (quads never straddle)
    float lsum = xsq;                    // loss: sum x^2 - 2*sum(score)
    float4 g0[4], g1[4];
    #pragma unroll
    for (int j = 0; j < 4; ++j) {
        const int r32 = (q & 7) * 4 + j;
        float kf = fmaxf(fmaxf(sKey[s][0][r32], sKey[s][1][r32]),
                         fmaxf(sKey[s][2][r32], sKey[s][3][r32]));
        const int code = (int)(f2u(kf) & 511u);
        if (cg == 0)
            lsum = fmaf(-2.f, u2f(f2u(kf) & 0xFFFFFE00u), lsum);
        const float* eq = emb + code * DD + 8 * cg;
        g0[j] = *(const float4*)eq;
        g1[j] = *(const float4*)(eq + 4);
    }
    float* ob = oblk + 4 * q;            // hw offset of the quad
    *(float4*)(ob + (size_t)(8*cg+0) * HWSZ) = make_float4(g0[0].x, g0[1].x, g0[2].x, g0[3].x);
    *(float4*)(ob + (size_t)(8*cg+1) * HWSZ) = make_float4(g0[0].y, g0[1].y, g0[2].y, g0[3].y);
    *(float4*)(ob + (size_t)(8*cg+2) * HWSZ) = make_float4(g0[0].z, g0[1].z, g0[2].z, g0[3].z);
    *(float4*)(ob + (size_t)(8*cg+3) * HWSZ) = make_float4(g0[0].w, g0[1].w, g0[2].w, g0[3].w);
    *(float4*)(ob + (size_t)(8*cg+4) * HWSZ) = make_float4(g1[0].x, g1[1].x, g1[2].x, g1[3].x);
    *(float4*)(ob + (size_t)(8*cg+5) * HWSZ) = make_float4(g1[0].y, g1[1].y, g1[2].y, g1[3].y);
    *(float4*)(ob + (size_t)(8*cg+6) * HWSZ) = make_float4(g1[0].z, g1[1].z, g1[2].z, g1[3].z);
    *(float4*)(ob + (size_t)(8*cg+7) * HWSZ) = make_float4(g1[0].w, g1[1].w, g1[2].w, g1[3].w);

    // ---- deterministic block loss reduction ----
    #pragma unroll
    for (int off = 32; off; off >>= 1) lsum += __shfl_down(lsum, off, 64);
    if (lane == 0) sRed[w] = lsum;
    __syncthreads();                     // #3
    if (tid == 0) partial[blockIdx.x] = (sRed[0] + sRed[1]) + (sRed[2] + sRed[3]);
}

__global__ __launch_bounds__(256) void vq_loss(
    const float* __restrict__ partial, float* __restrict__ loss)
{
    __shared__ float sRed[4];
    float v = 0.f;
    #pragma unroll
    for (int i = 0; i < NBLK / 256; ++i) v += partial[threadIdx.x + i * 256];
    #pragma unroll
    for (int off = 32; off; off >>= 1) v += __shfl_down(v, off, 64);
    if ((threadIdx.x & 63) == 0) sRed[threadIdx.x >> 6] = v;
    __syncthreads();
    if (threadIdx.x == 0)
        loss[0] = ((sRed[0] + sRed[1]) + (sRed[2] + sRed[3])) * (1.25f / 8388608.0f);
}

extern "C" void kernel_launch(void* const* d_in, const int* in_sizes, int n_in,
                              void* d_out, int out_size, void* d_ws, size_t ws_size,
                              hipStream_t stream) {
    const float* x   = (const float*)d_in[0];   // [32,64,64,64] NCHW
    const float* emb = (const float*)d_in[1];   // [512,64]
    float* out     = (float*)d_out;
    float* partial = (float*)d_ws;              // NBLK floats

    vq_mfma<<<NBLK, 256, 0, stream>>>(x, emb, out, partial);
    vq_loss<<<1, 256, 0, stream>>>(partial, out + (size_t)NROWS * DD);
}

// Round 6
// 32.650 us; speedup vs baseline: 9.3756x; 1.2190x over previous
//
#include <hip/hip_runtime.h>

// VQ-VAE quantization via fused bf16-MFMA argmin. 512 blocks x 256 rows,
// double-buffered 32-row sub-tiles, 1 barrier per sub-tile + 1 final barrier,
// single coalesced mega-epilogue. B=32, D=64, HW=4096, K=512.
// out[0..8388608)=quantized NCHW, out[8388608]=loss=1.25*mean((q-x)^2).
#define KK    512
#define DD    64
#define HWSZ  4096
#define NROWS 131072
#define RPB   256                  // rows per block
#define NSUB  8                    // 32-row sub-tiles per block
#define NBLK  (NROWS / RPB)        // 512

typedef short short8 __attribute__((ext_vector_type(8)));
typedef float f32x16 __attribute__((ext_vector_type(16)));

static __device__ __forceinline__ unsigned f2bf(float f) {
    unsigned u = __builtin_bit_cast(unsigned, f);
    return (u + 0x7FFFu + ((u >> 16) & 1u)) >> 16;          // RNE f32->bf16
}
static __device__ __forceinline__ unsigned pk2(float lo, float hi) {
    return f2bf(lo) | (f2bf(hi) << 16);                     // lo in bits 0..15
}
static __device__ __forceinline__ float    u2f(unsigned u) { return __builtin_bit_cast(float, u); }
static __device__ __forceinline__ unsigned f2u(float f)    { return __builtin_bit_cast(unsigned, f); }

// lgkm-only barrier: prefetch global loads stay in flight (no vmcnt drain)
#define LGKM0_BAR() do { asm volatile("s_waitcnt lgkmcnt(0)" ::: "memory"); \
                         __builtin_amdgcn_s_barrier();                      \
                         asm volatile("" ::: "memory"); } while (0)

__global__ __launch_bounds__(256, 3) void vq_mfma(
    const float* __restrict__ x, const float* __restrict__ emb,
    float* __restrict__ out, float* __restrict__ partial)
{
    __shared__ float    sH[KK];             // -0.5*||e_k||^2 (wave-private slices)
    __shared__ unsigned sX[2][32 * 32];     // double-buffered packed x sub-tile
    __shared__ float    sKey[NSUB][4][32];  // [subtile][wave][row] packed keys
    __shared__ float    sRed[4];

    const int tid  = threadIdx.x;
    const int lane = tid & 63;
    const int w    = tid >> 6;              // wave owns codes [w*128, w*128+128)
    const int g    = lane >> 5;
    const int wbase = w * 128;

    const int base = blockIdx.x * RPB;      // 256 consecutive hw rows, b constant
    const int b    = base >> 12;
    const int hwb  = base & 4095;
    const float* xblk = x   + (size_t)b * (DD * HWSZ) + hwb;
    float*       oblk = out + (size_t)b * (DD * HWSZ) + hwb;

    const int cp  = tid >> 3;               // staging: channel pair 0..31
    const int hwq = (tid & 7) * 4;          // staging: hw quad

    // ---- issue sub-tile 0 loads first (latency hidden under A-frag setup) ----
    float4 Aa = *(const float4*)(xblk + (size_t)(2*cp)   * HWSZ + hwq);
    float4 Ab = *(const float4*)(xblk + (size_t)(2*cp+1) * HWSZ + hwq);
    float4 Na, Nb;

    // ---- persistent codebook A-fragments; -e^2/2 (wave-private, no barrier) ----
    short8 afrag[4][4];
    #pragma unroll
    for (int ct = 0; ct < 4; ++ct) {
        const int code = wbase + ct * 32 + (lane & 31);
        float e2h = 0.f;
        #pragma unroll
        for (int m = 0; m < 4; ++m) {
            const float* ep = emb + code * DD + m * 16 + 8 * g;
            float4 a  = *(const float4*)ep;
            float4 b4 = *(const float4*)(ep + 4);
            union { unsigned u[4]; short8 s; } cv;
            cv.u[0] = pk2(a.x, a.y);   cv.u[1] = pk2(a.z, a.w);
            cv.u[2] = pk2(b4.x, b4.y); cv.u[3] = pk2(b4.z, b4.w);
            afrag[ct][m] = cv.s;
            e2h = fmaf(a.x,a.x,e2h);   e2h = fmaf(a.y,a.y,e2h);
            e2h = fmaf(a.z,a.z,e2h);   e2h = fmaf(a.w,a.w,e2h);
            e2h = fmaf(b4.x,b4.x,e2h); e2h = fmaf(b4.y,b4.y,e2h);
            e2h = fmaf(b4.z,b4.z,e2h); e2h = fmaf(b4.w,b4.w,e2h);
        }
        float e2f = e2h + __shfl_xor(e2h, 32, 64);
        if (lane < 32) sH[code] = -0.5f * e2f;
    }

    float xsq = 0.f;

    // ---- sub-tile body: stage -> prefetch next -> barrier -> MFMA+keys ----
#define BODY(CA, CB, NA, NB, S, BUF)                                          \
    do {                                                                      \
        uint4 dw = { pk2(CA.x, CB.x), pk2(CA.y, CB.y),                        \
                     pk2(CA.z, CB.z), pk2(CA.w, CB.w) };                      \
        *(uint4*)&sX[BUF][cp * 32 + hwq] = dw;                                \
        xsq = fmaf(CA.x,CA.x,xsq); xsq = fmaf(CA.y,CA.y,xsq);                 \
        xsq = fmaf(CA.z,CA.z,xsq); xsq = fmaf(CA.w,CA.w,xsq);                 \
        xsq = fmaf(CB.x,CB.x,xsq); xsq = fmaf(CB.y,CB.y,xsq);                 \
        xsq = fmaf(CB.z,CB.z,xsq); xsq = fmaf(CB.w,CB.w,xsq);                 \
        if ((S) + 1 < NSUB) {                                                 \
            const float* xn = xblk + 32 * ((S) + 1);                          \
            NA = *(const float4*)(xn + (size_t)(2*cp)   * HWSZ + hwq);        \
            NB = *(const float4*)(xn + (size_t)(2*cp+1) * HWSZ + hwq);        \
        }                                                                     \
        LGKM0_BAR();                                                          \
        short8 bfrag[4];                                                      \
        _Pragma("unroll")                                                     \
        for (int m = 0; m < 4; ++m) {                                         \
            const unsigned* sp = &sX[BUF][(m * 8 + 4 * g) * 32 + (lane & 31)];\
            union { unsigned u[4]; short8 s8; } cv;                           \
            cv.u[0] = sp[0]; cv.u[1] = sp[32];                                \
            cv.u[2] = sp[64]; cv.u[3] = sp[96];                               \
            bfrag[m] = cv.s8;                                                 \
        }                                                                     \
        float kwave;                                                          \
        _Pragma("unroll")                                                     \
        for (int ct = 0; ct < 4; ++ct) {                                      \
            f32x16 acc;                                                       \
            _Pragma("unroll")                                                 \
            for (int i = 0; i < 4; ++i) {                                     \
                float4 h = *(const float4*)(sH + wbase + ct*32 + 4*g + 8*i);  \
                acc[4*i]   = h.x; acc[4*i+1] = h.y;                           \
                acc[4*i+2] = h.z; acc[4*i+3] = h.w;                           \
            }                                                                 \
            _Pragma("unroll")                                                 \
            for (int m = 0; m < 4; ++m)                                       \
                acc = __builtin_amdgcn_mfma_f32_32x32x16_bf16(                \
                          afrag[ct][m], bfrag[m], acc, 0, 0, 0);              \
            float km;                                                         \
            _Pragma("unroll")                                                 \
            for (int r = 0; r < 16; ++r) {                                    \
                unsigned key = (f2u(acc[r]) & 0xFFFFFE00u) |                  \
                               (unsigned)((r & 3) + 8 * (r >> 2) + 4 * g);    \
                float fk = u2f(key);                                          \
                km = r ? fmaxf(km, fk) : fk;                                  \
            }                                                                 \
            unsigned kb = (f2u(km) & 0xFFFFFE00u) |                          \
                          (unsigned)((ct) << 5) | (f2u(km) & 31u);            \
            float fkb = u2f(kb);                                              \
            kwave = ct ? fmaxf(kwave, fkb) : fkb;                             \
        }                                                                     \
        float k2 = fmaxf(kwave, __shfl_xor(kwave, 32, 64));                   \
        unsigned kb2 = (f2u(k2) & 0xFFFFFE00u) |                              \
                       (unsigned)(w << 7) | (f2u(k2) & 127u);                 \
        if (lane < 32) sKey[S][w][lane] = u2f(kb2);                           \
    } while (0)

    for (int ss = 0; ss < NSUB / 2; ++ss) {
        BODY(Aa, Ab, Na, Nb, 2 * ss,     0);
        BODY(Na, Nb, Aa, Ab, 2 * ss + 1, 1);
    }
#undef BODY

    LGKM0_BAR();                            // all sKey slices ready

    // ---- mega-epilogue: thread = (quad 0..63, 16-channel group 0..3) ----
    const int quad = tid & 63;              // rows 4*quad .. 4*quad+3
    const int cgrp = tid >> 6;              // channels 16*cgrp .. 16*cgrp+15
    const int s    = quad >> 3;             // sub-tile of this quad
    float lsum = xsq;                       // loss: sum x^2 - 2*sum(best score)
    float gq[4][16];
    #pragma unroll
    for (int j = 0; j < 4; ++j) {
        const int r32 = (quad & 7) * 4 + j;
        float kf = fmaxf(fmaxf(sKey[s][0][r32], sKey[s][1][r32]),
                         fmaxf(sKey[s][2][r32], sKey[s][3][r32]));
        const int code = (int)(f2u(kf) & 511u);
        if (cgrp == 0)
            lsum = fmaf(-2.f, u2f(f2u(kf) & 0xFFFFFE00u), lsum);
        const float* eq = emb + code * DD + 16 * cgrp;
        float4 e0 = *(const float4*)eq;
        float4 e1 = *(const float4*)(eq + 4);
        float4 e2 = *(const float4*)(eq + 8);
        float4 e3 = *(const float4*)(eq + 12);
        gq[j][ 0] = e0.x; gq[j][ 1] = e0.y; gq[j][ 2] = e0.z; gq[j][ 3] = e0.w;
        gq[j][ 4] = e1.x; gq[j][ 5] = e1.y; gq[j][ 6] = e1.z; gq[j][ 7] = e1.w;
        gq[j][ 8] = e2.x; gq[j][ 9] = e2.y; gq[j][10] = e2.z; gq[j][11] = e2.w;
        gq[j][12] = e3.x; gq[j][13] = e3.y; gq[j][14] = e3.z; gq[j][15] = e3.w;
    }
    float* ob = oblk + 4 * quad;
    #pragma unroll
    for (int c = 0; c < 16; ++c) {
        float4 v = make_float4(gq[0][c], gq[1][c], gq[2][c], gq[3][c]);
        *(float4*)(ob + (size_t)(16 * cgrp + c) * HWSZ) = v;   // 1KB/channel/wave
    }

    // ---- deterministic block loss reduction ----
    #pragma unroll
    for (int off = 32; off; off >>= 1) lsum += __shfl_down(lsum, off, 64);
    if (lane == 0) sRed[w] = lsum;
    __syncthreads();
    if (tid == 0) partial[blockIdx.x] = (sRed[0] + sRed[1]) + (sRed[2] + sRed[3]);
}

__global__ __launch_bounds__(256) void vq_loss(
    const float* __restrict__ partial, float* __restrict__ loss)
{
    __shared__ float sRed[4];
    float v = 0.f;
    #pragma unroll
    for (int i = 0; i < NBLK / 256; ++i) v += partial[threadIdx.x + i * 256];
    #pragma unroll
    for (int off = 32; off; off >>= 1) v += __shfl_down(v, off, 64);
    if ((threadIdx.x & 63) == 0) sRed[threadIdx.x >> 6] = v;
    __syncthreads();
    if (threadIdx.x == 0)
        loss[0] = ((sRed[0] + sRed[1]) + (sRed[2] + sRed[3])) * (1.25f / 8388608.0f);
}

extern "C" void kernel_launch(void* const* d_in, const int* in_sizes, int n_in,
                              void* d_out, int out_size, void* d_ws, size_t ws_size,
                              hipStream_t stream) {
    const float* x   = (const float*)d_in[0];   // [32,64,64,64] NCHW
    const float* emb = (const float*)d_in[1];   // [512,64]
    float* out     = (float*)d_out;
    float* partial = (float*)d_ws;              // NBLK floats

    vq_mfma<<<NBLK, 256, 0, stream>>>(x, emb, out, partial);
    vq_loss<<<1, 256, 0, stream>>>(partial, out + (size_t)NROWS * DD);
}

// Round 7
// 30.995 us; speedup vs baseline: 9.8761x; 1.0534x over previous
//
#include <hip/hip_runtime.h>

// VQ-VAE quantization via fused bf16-MFMA argmin. 512 blocks x 256 rows,
// whole tile staged at once, ONE barrier before compute, one before epilogue.
// B=32, D=64, HW=4096, K=512.
// out[0..8388608)=quantized NCHW, out[8388608]=loss=1.25*mean((q-x)^2).
#define KK    512
#define DD    64
#define HWSZ  4096
#define NROWS 131072
#define RPB   256                  // rows per block
#define NSUB  8                    // 32-row sub-tiles per block
#define NBLK  (NROWS / RPB)        // 512

typedef short short8 __attribute__((ext_vector_type(8)));
typedef float f32x16 __attribute__((ext_vector_type(16)));

static __device__ __forceinline__ unsigned cvtpk(float lo, float hi) {
    unsigned r;                    // r = bf16(lo) | bf16(hi)<<16, RNE
    asm("v_cvt_pk_bf16_f32 %0, %1, %2" : "=v"(r) : "v"(lo), "v"(hi));
    return r;
}
static __device__ __forceinline__ float    u2f(unsigned u) { return __builtin_bit_cast(float, u); }
static __device__ __forceinline__ unsigned f2u(float f)    { return __builtin_bit_cast(unsigned, f); }
static __device__ __forceinline__ float mx3(float a, float b, float c) {
    return fmaxf(fmaxf(a, b), c);  // clang fuses to v_max3_f32
}

// lgkm-only barrier: global prefetch loads stay in flight (no vmcnt drain)
#define LGKM0_BAR() do { asm volatile("s_waitcnt lgkmcnt(0)" ::: "memory"); \
                         __builtin_amdgcn_s_barrier();                      \
                         asm volatile("" ::: "memory"); } while (0)

__global__ __launch_bounds__(256, 2) void vq_mfma(
    const float* __restrict__ x, const float* __restrict__ emb,
    float* __restrict__ out, float* __restrict__ partial)
{
    __shared__ float    sH[KK];             // -0.5*||e_k||^2 (wave-private slices)
    __shared__ unsigned sX[NSUB][32 * 32];  // 32 KB: whole 256-row tile, packed bf16
    __shared__ float    sKey[NSUB][4][32];  // [subtile][wave][row] packed keys
    __shared__ float    sRed[4];

    const int tid  = threadIdx.x;
    const int lane = tid & 63;
    const int w    = tid >> 6;              // wave owns codes [w*128, w*128+128)
    const int g    = lane >> 5;
    const int wbase = w * 128;

    const int base = blockIdx.x * RPB;      // 256 consecutive hw rows, b constant
    const int b    = base >> 12;
    const int hwb  = base & 4095;
    const float* xblk = x   + (size_t)b * (DD * HWSZ) + hwb;
    float*       oblk = out + (size_t)b * (DD * HWSZ) + hwb;

    const int cp  = tid >> 3;               // staging: channel pair 0..31
    const int hwq = (tid & 7) * 4;          // staging: hw quad

    // ---- issue ALL x loads up front; latency hidden under A-frag setup ----
    float4 xa[NSUB], xbv[NSUB];
    #pragma unroll
    for (int s = 0; s < NSUB; ++s) {
        const float* xs = xblk + 32 * s;
        xa[s]  = *(const float4*)(xs + (size_t)(2*cp)   * HWSZ + hwq);
        xbv[s] = *(const float4*)(xs + (size_t)(2*cp+1) * HWSZ + hwq);
    }

    // ---- persistent codebook A-fragments; -e^2/2 (wave-private, no barrier) ----
    short8 afrag[4][4];
    #pragma unroll
    for (int ct = 0; ct < 4; ++ct) {
        const int code = wbase + ct * 32 + (lane & 31);
        float e2h = 0.f;
        #pragma unroll
        for (int m = 0; m < 4; ++m) {
            const float* ep = emb + code * DD + m * 16 + 8 * g;
            float4 a  = *(const float4*)ep;
            float4 b4 = *(const float4*)(ep + 4);
            union { unsigned u[4]; short8 s; } cv;
            cv.u[0] = cvtpk(a.x, a.y);   cv.u[1] = cvtpk(a.z, a.w);
            cv.u[2] = cvtpk(b4.x, b4.y); cv.u[3] = cvtpk(b4.z, b4.w);
            afrag[ct][m] = cv.s;
            e2h = fmaf(a.x,a.x,e2h);   e2h = fmaf(a.y,a.y,e2h);
            e2h = fmaf(a.z,a.z,e2h);   e2h = fmaf(a.w,a.w,e2h);
            e2h = fmaf(b4.x,b4.x,e2h); e2h = fmaf(b4.y,b4.y,e2h);
            e2h = fmaf(b4.z,b4.z,e2h); e2h = fmaf(b4.w,b4.w,e2h);
        }
        float e2f = e2h + __shfl_xor(e2h, 32, 64);
        if (lane < 32) sH[code] = -0.5f * e2f;
    }

    // ---- pack whole tile -> sX; thread-local fp32 sum(x^2) ----
    float xsq = 0.f;
    #pragma unroll
    for (int s = 0; s < NSUB; ++s) {
        float4 fa = xa[s], fb = xbv[s];
        uint4 dw = { cvtpk(fa.x, fb.x), cvtpk(fa.y, fb.y),
                     cvtpk(fa.z, fb.z), cvtpk(fa.w, fb.w) };
        *(uint4*)&sX[s][cp * 32 + hwq] = dw;
        xsq = fmaf(fa.x,fa.x,xsq); xsq = fmaf(fa.y,fa.y,xsq);
        xsq = fmaf(fa.z,fa.z,xsq); xsq = fmaf(fa.w,fa.w,xsq);
        xsq = fmaf(fb.x,fb.x,xsq); xsq = fmaf(fb.y,fb.y,xsq);
        xsq = fmaf(fb.z,fb.z,xsq); xsq = fmaf(fb.w,fb.w,xsq);
    }

    // ---- hoist acc-init to registers (wave-own sH slice, read once) ----
    float4 e2r[4][4];
    #pragma unroll
    for (int ct = 0; ct < 4; ++ct)
        #pragma unroll
        for (int i = 0; i < 4; ++i)
            e2r[ct][i] = *(const float4*)(sH + wbase + ct * 32 + 4 * g + 8 * i);

    LGKM0_BAR();                            // #1: all sX staged (sH wave-private)

    const unsigned cbase = (unsigned)(wbase + 4 * g);

    // ---- 8 sub-tiles back-to-back, ZERO barriers between ----
    #pragma unroll 1
    for (int s = 0; s < NSUB; ++s) {
        short8 bfrag[4];
        #pragma unroll
        for (int m = 0; m < 4; ++m) {
            const unsigned* sp = &sX[s][(m * 8 + 4 * g) * 32 + (lane & 31)];
            union { unsigned u[4]; short8 s8; } cv;
            cv.u[0] = sp[0]; cv.u[1] = sp[32]; cv.u[2] = sp[64]; cv.u[3] = sp[96];
            bfrag[m] = cv.s8;
        }
        float kwave;
        #pragma unroll
        for (int ct = 0; ct < 4; ++ct) {
            f32x16 acc;
            #pragma unroll
            for (int i = 0; i < 4; ++i) {
                acc[4*i]   = e2r[ct][i].x; acc[4*i+1] = e2r[ct][i].y;
                acc[4*i+2] = e2r[ct][i].z; acc[4*i+3] = e2r[ct][i].w;
            }
            #pragma unroll
            for (int m = 0; m < 4; ++m)
                acc = __builtin_amdgcn_mfma_f32_32x32x16_bf16(afrag[ct][m], bfrag[m], acc, 0, 0, 0);
            // keys carry the FULL 9-bit code (w,ct,row): no post-shfl rebuild
            float k[16];
            #pragma unroll
            for (int r = 0; r < 16; ++r)
                k[r] = u2f((f2u(acc[r]) & 0xFFFFFE00u) |
                           (cbase + (unsigned)(ct * 32 + (r & 3) + 8 * (r >> 2))));
            float t0 = mx3(k[0],  k[1],  k[2]);
            float t1 = mx3(k[3],  k[4],  k[5]);
            float t2 = mx3(k[6],  k[7],  k[8]);
            float t3 = mx3(k[9],  k[10], k[11]);
            float t4 = mx3(k[12], k[13], k[14]);
            float kct = mx3(mx3(t0, t1, k[15]), fmaxf(t2, t3), t4);
            kwave = ct ? fmaxf(kwave, kct) : kct;
        }
        float k2 = fmaxf(kwave, __shfl_xor(kwave, 32, 64));
        if (lane < 32) sKey[s][w][lane] = k2;
    }

    LGKM0_BAR();                            // #2: all sKey slices ready

    // ---- mega-epilogue: thread = (quad 0..63, 16-channel group 0..3) ----
    const int quad = tid & 63;              // rows 4*quad .. 4*quad+3
    const int cgrp = tid >> 6;              // channels 16*cgrp .. 16*cgrp+15
    const int s    = quad >> 3;             // sub-tile of this quad
    float lsum = xsq;                       // loss: sum x^2 - 2*sum(best score)
    float gq[4][16];
    #pragma unroll
    for (int j = 0; j < 4; ++j) {
        const int r32 = (quad & 7) * 4 + j;
        float kf = fmaxf(fmaxf(sKey[s][0][r32], sKey[s][1][r32]),
                         fmaxf(sKey[s][2][r32], sKey[s][3][r32]));
        const int code = (int)(f2u(kf) & 511u);
        if (cgrp == 0)
            lsum = fmaf(-2.f, u2f(f2u(kf) & 0xFFFFFE00u), lsum);
        const float* eq = emb + code * DD + 16 * cgrp;
        float4 e0 = *(const float4*)eq;
        float4 e1 = *(const float4*)(eq + 4);
        float4 e2 = *(const float4*)(eq + 8);
        float4 e3 = *(const float4*)(eq + 12);
        gq[j][ 0] = e0.x; gq[j][ 1] = e0.y; gq[j][ 2] = e0.z; gq[j][ 3] = e0.w;
        gq[j][ 4] = e1.x; gq[j][ 5] = e1.y; gq[j][ 6] = e1.z; gq[j][ 7] = e1.w;
        gq[j][ 8] = e2.x; gq[j][ 9] = e2.y; gq[j][10] = e2.z; gq[j][11] = e2.w;
        gq[j][12] = e3.x; gq[j][13] = e3.y; gq[j][14] = e3.z; gq[j][15] = e3.w;
    }
    float* ob = oblk + 4 * quad;
    #pragma unroll
    for (int c = 0; c < 16; ++c) {
        float4 v = make_float4(gq[0][c], gq[1][c], gq[2][c], gq[3][c]);
        *(float4*)(ob + (size_t)(16 * cgrp + c) * HWSZ) = v;   // 1KB/channel/wave
    }

    // ---- deterministic block loss reduction ----
    #pragma unroll
    for (int off = 32; off; off >>= 1) lsum += __shfl_down(lsum, off, 64);
    if (lane == 0) sRed[w] = lsum;
    __syncthreads();
    if (tid == 0) partial[blockIdx.x] = (sRed[0] + sRed[1]) + (sRed[2] + sRed[3]);
}

__global__ __launch_bounds__(256) void vq_loss(
    const float* __restrict__ partial, float* __restrict__ loss)
{
    __shared__ float sRed[4];
    float v = 0.f;
    #pragma unroll
    for (int i = 0; i < NBLK / 256; ++i) v += partial[threadIdx.x + i * 256];
    #pragma unroll
    for (int off = 32; off; off >>= 1) v += __shfl_down(v, off, 64);
    if ((threadIdx.x & 63) == 0) sRed[threadIdx.x >> 6] = v;
    __syncthreads();
    if (threadIdx.x == 0)
        loss[0] = ((sRed[0] + sRed[1]) + (sRed[2] + sRed[3])) * (1.25f / 8388608.0f);
}

extern "C" void kernel_launch(void* const* d_in, const int* in_sizes, int n_in,
                              void* d_out, int out_size, void* d_ws, size_t ws_size,
                              hipStream_t stream) {
    const float* x   = (const float*)d_in[0];   // [32,64,64,64] NCHW
    const float* emb = (const float*)d_in[1];   // [512,64]
    float* out     = (float*)d_out;
    float* partial = (float*)d_ws;              // NBLK floats

    vq_mfma<<<NBLK, 256, 0, stream>>>(x, emb, out, partial);
    vq_loss<<<1, 256, 0, stream>>>(partial, out + (size_t)NROWS * DD);
}